// Round 9
// baseline (107.274 us; speedup 1.0000x reference)
//
#include <hip/hip_runtime.h>
#include <math.h>

// LaplacianBuilder: N=2048 nodes, DEG=16, D=4, E=32768 (2E=65536 directed)
// out = dense (8192 x 8192) fp32, 256 MB.
// v9: R4 structure exactly (94.8us proven); SINGLE change: writer stores are
// nontemporal (bypass L2 write-allocate; output is write-once, never re-read).
// Writer loop shape, colmap type, everything else = R4 verbatim.

#define NNODES 2048
#define MAXDEG 96   // per-node directed-degree capacity (mean 32, huge margin)
#define BLK 256

typedef float vfloat4 __attribute__((ext_vector_type(4)));

// ---------------------------------------------------------------------------
// K1: per directed edge e in [0,2E): append (nbr<<20 | t<<19 | u) to
// list[ei[0][e]].  t=1 for the reverse half (e>=E), u = undirected index.
// ---------------------------------------------------------------------------
__global__ void build_lists_kernel(const int* __restrict__ ei,
                                   int* __restrict__ lists,
                                   int* __restrict__ cnts,
                                   int E, int twoE) {
    int e = blockIdx.x * blockDim.x + threadIdx.x;
    if (e >= twoE) return;
    int node = ei[e];
    int nbr = ei[twoE + e];
    int t = (e >= E) ? 1 : 0;
    int u = t ? (e - E) : e;
    int slot = atomicAdd(&cnts[node], 1);
    if (slot < MAXDEG)
        lists[(size_t)node * MAXDEG + slot] = (nbr << 20) | (t << 19) | u;
}

// ---------------------------------------------------------------------------
// Jacobi rotation on (P,Q), compile-time indices -> stays in registers
// ---------------------------------------------------------------------------
template <int P, int Q>
__device__ __forceinline__ void jrot(float a[4][4], float v[4][4]) {
    float apq = a[P][Q];
    if (fabsf(apq) < 1e-12f) return;
    float theta = (a[Q][Q] - a[P][P]) / (2.0f * apq);
    float t = 1.0f / (fabsf(theta) + sqrtf(theta * theta + 1.0f));
    t = (theta < 0.0f) ? -t : t;
    float c = 1.0f / sqrtf(t * t + 1.0f);
    float s = t * c;
    #pragma unroll
    for (int k = 0; k < 4; ++k) {
        float akp = a[k][P], akq = a[k][Q];
        a[k][P] = c * akp - s * akq;
        a[k][Q] = s * akp + c * akq;
    }
    #pragma unroll
    for (int k = 0; k < 4; ++k) {
        float apk = a[P][k], aqk = a[Q][k];
        a[P][k] = c * apk - s * aqk;
        a[Q][k] = s * apk + c * aqk;
    }
    #pragma unroll
    for (int k = 0; k < 4; ++k) {
        float vkp = v[k][P], vkq = v[k][Q];
        v[k][P] = c * vkp - s * vkq;
        v[k][Q] = s * vkp + c * vkq;
    }
}

// ---------------------------------------------------------------------------
// K2: per node: gather-sum Gram over listed directed edges, eigh(G+I) via
// 6 Jacobi sweeps, S=(G+I)^(-1/2), vdiag = clip(S G S, -1, 1).
// ---------------------------------------------------------------------------
__global__ void __launch_bounds__(64)
node_kernel(const float* __restrict__ maps,
            const int* __restrict__ lists,
            const int* __restrict__ cnts,
            float* __restrict__ Smat,
            float* __restrict__ vdiag,
            int E, int n) {
    int node = blockIdx.x * blockDim.x + threadIdx.x;
    if (node >= n) return;
    float gm[4][4];
    #pragma unroll
    for (int i = 0; i < 4; ++i)
        #pragma unroll
        for (int j = 0; j < 4; ++j) gm[i][j] = 0.0f;
    int cnt = cnts[node];
    if (cnt > MAXDEG) cnt = MAXDEG;
    const int* myl = lists + (size_t)node * MAXDEG;
    #pragma unroll 4
    for (int j = 0; j < cnt; ++j) {
        int entry = myl[j];
        int t = (entry >> 19) & 1;
        int u = entry & 0x7FFF;
        int e = t ? (E + u) : u;
        const float4* mp = reinterpret_cast<const float4*>(maps + (size_t)e * 16);
        float4 q0 = mp[0], q1 = mp[1], q2 = mp[2], q3 = mp[3];
        float m[4][4] = {{q0.x, q0.y, q0.z, q0.w}, {q1.x, q1.y, q1.z, q1.w},
                         {q2.x, q2.y, q2.z, q2.w}, {q3.x, q3.y, q3.z, q3.w}};
        #pragma unroll
        for (int i = 0; i < 4; ++i)
            #pragma unroll
            for (int jj = 0; jj < 4; ++jj)
                gm[i][jj] += m[0][i] * m[0][jj] + m[1][i] * m[1][jj] +
                             m[2][i] * m[2][jj] + m[3][i] * m[3][jj];
    }
    float a[4][4], v[4][4];
    #pragma unroll
    for (int i = 0; i < 4; ++i)
        #pragma unroll
        for (int j = 0; j < 4; ++j) {
            a[i][j] = gm[i][j] + (i == j ? 1.0f : 0.0f);
            v[i][j] = (i == j) ? 1.0f : 0.0f;
        }
    #pragma unroll
    for (int sweep = 0; sweep < 6; ++sweep) {
        jrot<0, 1>(a, v); jrot<0, 2>(a, v); jrot<0, 3>(a, v);
        jrot<1, 2>(a, v); jrot<1, 3>(a, v); jrot<2, 3>(a, v);
    }
    float ir[4];
    #pragma unroll
    for (int m = 0; m < 4; ++m)
        ir[m] = 1.0f / sqrtf(fmaxf(a[m][m], 1e-8f));
    float s[4][4];
    #pragma unroll
    for (int i = 0; i < 4; ++i)
        #pragma unroll
        for (int j = 0; j < 4; ++j)
            s[i][j] = v[i][0] * v[j][0] * ir[0] + v[i][1] * v[j][1] * ir[1] +
                      v[i][2] * v[j][2] * ir[2] + v[i][3] * v[j][3] * ir[3];
    float4* sp = reinterpret_cast<float4*>(Smat + (size_t)node * 16);
    sp[0] = make_float4(s[0][0], s[0][1], s[0][2], s[0][3]);
    sp[1] = make_float4(s[1][0], s[1][1], s[1][2], s[1][3]);
    sp[2] = make_float4(s[2][0], s[2][1], s[2][2], s[2][3]);
    sp[3] = make_float4(s[3][0], s[3][1], s[3][2], s[3][3]);
    float t1[4][4];
    #pragma unroll
    for (int i = 0; i < 4; ++i)
        #pragma unroll
        for (int j = 0; j < 4; ++j)
            t1[i][j] = s[i][0] * gm[0][j] + s[i][1] * gm[1][j] +
                       s[i][2] * gm[2][j] + s[i][3] * gm[3][j];
    float4* vp = reinterpret_cast<float4*>(vdiag + (size_t)node * 16);
    #pragma unroll
    for (int i = 0; i < 4; ++i) {
        float r0 = t1[i][0] * s[0][0] + t1[i][1] * s[1][0] + t1[i][2] * s[2][0] + t1[i][3] * s[3][0];
        float r1 = t1[i][0] * s[0][1] + t1[i][1] * s[1][1] + t1[i][2] * s[2][1] + t1[i][3] * s[3][1];
        float r2 = t1[i][0] * s[0][2] + t1[i][1] * s[1][2] + t1[i][2] * s[2][2] + t1[i][3] * s[3][2];
        float r3 = t1[i][0] * s[0][3] + t1[i][1] * s[1][3] + t1[i][2] * s[2][3] + t1[i][3] * s[3][3];
        vp[i] = make_float4(fminf(fmaxf(r0, -1.0f), 1.0f),
                            fminf(fmaxf(r1, -1.0f), 1.0f),
                            fminf(fmaxf(r2, -1.0f), 1.0f),
                            fminf(fmaxf(r3, -1.0f), 1.0f));
    }
}

// ---------------------------------------------------------------------------
// K3: streaming writer (R4 structure verbatim; ONLY the stores are nt).
// One workgroup per block-row r: fused sandwich for <=cnt listed edges,
// O(1) int LDS colmap, then ri-outer stream of 4 x 8192 floats.
// ---------------------------------------------------------------------------
__global__ void __launch_bounds__(BLK)
writer_kernel(const float* __restrict__ maps,
              const int* __restrict__ lists,
              const int* __restrict__ cnts,
              const float* __restrict__ Smat,
              const float* __restrict__ vdiag,
              float* __restrict__ out, int E, int ld) {
    int r = blockIdx.x;
    int tid = threadIdx.x;
    __shared__ int colmap[NNODES];               // 8 KB
    __shared__ vfloat4 s_dat[MAXDEG + 1][4];     // ~6.2 KB
    for (int i = tid; i < NNODES; i += BLK) colmap[i] = -1;

    int cnt = cnts[r];
    if (cnt > MAXDEG) cnt = MAXDEG;
    int col = -1, t = 0;
    if (tid < cnt) {
        int entry = lists[(size_t)r * MAXDEG + tid];
        col = entry >> 20;
        t = (entry >> 19) & 1;
        int u = entry & 0x7FFF;
        const float4* ap = reinterpret_cast<const float4*>(maps + (size_t)u * 16);
        const float4* bp = reinterpret_cast<const float4*>(maps + (size_t)(E + u) * 16);
        float4 a0 = ap[0], a1 = ap[1], a2 = ap[2], a3 = ap[3];
        float4 b0 = bp[0], b1 = bp[1], b2 = bp[2], b3 = bp[3];
        float A[4][4] = {{a0.x, a0.y, a0.z, a0.w}, {a1.x, a1.y, a1.z, a1.w},
                         {a2.x, a2.y, a2.z, a2.w}, {a3.x, a3.y, a3.z, a3.w}};
        float B[4][4] = {{b0.x, b0.y, b0.z, b0.w}, {b1.x, b1.y, b1.z, b1.w},
                         {b2.x, b2.y, b2.z, b2.w}, {b3.x, b3.y, b3.z, b3.w}};
        float C[4][4];
        #pragma unroll
        for (int i = 0; i < 4; ++i)
            #pragma unroll
            for (int j = 0; j < 4; ++j)
                C[i][j] = A[0][i] * B[0][j] + A[1][i] * B[1][j] +
                          A[2][i] * B[2][j] + A[3][i] * B[3][j];
        int rn = t ? col : r;
        int cn = t ? r : col;
        const float4* srp = reinterpret_cast<const float4*>(Smat + (size_t)rn * 16);
        const float4* scp = reinterpret_cast<const float4*>(Smat + (size_t)cn * 16);
        float4 s0 = srp[0], s1 = srp[1], s2 = srp[2], s3 = srp[3];
        float Sr[4][4] = {{s0.x, s0.y, s0.z, s0.w}, {s1.x, s1.y, s1.z, s1.w},
                          {s2.x, s2.y, s2.z, s2.w}, {s3.x, s3.y, s3.z, s3.w}};
        float4 c0 = scp[0], c1 = scp[1], c2 = scp[2], c3 = scp[3];
        float Sc[4][4] = {{c0.x, c0.y, c0.z, c0.w}, {c1.x, c1.y, c1.z, c1.w},
                          {c2.x, c2.y, c2.z, c2.w}, {c3.x, c3.y, c3.z, c3.w}};
        float t1m[4][4];
        #pragma unroll
        for (int i = 0; i < 4; ++i)
            #pragma unroll
            for (int j = 0; j < 4; ++j)
                t1m[i][j] = Sr[i][0] * C[0][j] + Sr[i][1] * C[1][j] +
                            Sr[i][2] * C[2][j] + Sr[i][3] * C[3][j];
        float W[4][4];
        #pragma unroll
        for (int i = 0; i < 4; ++i)
            #pragma unroll
            for (int j = 0; j < 4; ++j) {
                float x = t1m[i][0] * Sc[0][j] + t1m[i][1] * Sc[1][j] +
                          t1m[i][2] * Sc[2][j] + t1m[i][3] * Sc[3][j];
                W[i][j] = -fminf(fmaxf(x, -1.0f), 1.0f);
            }
        if (t) {   // block (r,col) = W^T
            s_dat[tid][0] = (vfloat4){W[0][0], W[1][0], W[2][0], W[3][0]};
            s_dat[tid][1] = (vfloat4){W[0][1], W[1][1], W[2][1], W[3][1]};
            s_dat[tid][2] = (vfloat4){W[0][2], W[1][2], W[2][2], W[3][2]};
            s_dat[tid][3] = (vfloat4){W[0][3], W[1][3], W[2][3], W[3][3]};
        } else {
            s_dat[tid][0] = (vfloat4){W[0][0], W[0][1], W[0][2], W[0][3]};
            s_dat[tid][1] = (vfloat4){W[1][0], W[1][1], W[1][2], W[1][3]};
            s_dat[tid][2] = (vfloat4){W[2][0], W[2][1], W[2][2], W[2][3]};
            s_dat[tid][3] = (vfloat4){W[3][0], W[3][1], W[3][2], W[3][3]};
        }
    }
    if (tid < 4) {
        float4 dv = reinterpret_cast<const float4*>(vdiag + (size_t)r * 16)[tid];
        s_dat[MAXDEG][tid] = (vfloat4){dv.x, dv.y, dv.z, dv.w};
    }
    __syncthreads();                           // colmap cleared + s_dat ready
    if (tid < cnt && !t) colmap[col] = tid;
    __syncthreads();                           // t=0 placed
    if (tid < cnt && t) colmap[col] = tid;     // t=1 wins (reference order)
    if (tid == 0) colmap[r] = MAXDEG;          // diag (no self-edges)
    __syncthreads();

    size_t base = (size_t)(r * 4) * (size_t)ld;
    const vfloat4 zero = (vfloat4){0.f, 0.f, 0.f, 0.f};
    #pragma unroll
    for (int ri = 0; ri < 4; ++ri) {
        vfloat4* orow = reinterpret_cast<vfloat4*>(out + base + (size_t)ri * ld);
        for (int cb = tid; cb < NNODES; cb += BLK) {
            int sl = colmap[cb];
            vfloat4 val = zero;
            if (sl >= 0) val = s_dat[sl][ri];
            __builtin_nontemporal_store(val, &orow[cb]);
        }
    }
}

extern "C" void kernel_launch(void* const* d_in, const int* in_sizes, int n_in,
                              void* d_out, int out_size, void* d_ws, size_t ws_size,
                              hipStream_t stream) {
    const float* maps = (const float*)d_in[0];
    const int* ei = (const int*)d_in[1];   // (2, 2E) int32
    int twoE = in_sizes[0] / 16;           // 65536
    int E = twoE / 2;                      // 32768
    int n = NNODES;
    int ld = n * 4;                        // 8192
    float* out = (float*)d_out;

    int*   ws_cnt  = (int*)d_ws;                              // n ints
    int*   ws_list = ws_cnt + n;                              // n*MAXDEG ints
    float* ws_S    = (float*)(ws_list + (size_t)n * MAXDEG);  // n*16 floats
    float* ws_vd   = ws_S + (size_t)n * 16;                   // n*16 floats

    (void)hipMemsetAsync(ws_cnt, 0, (size_t)n * sizeof(int), stream);
    build_lists_kernel<<<(twoE + BLK - 1) / BLK, BLK, 0, stream>>>(
        ei, ws_list, ws_cnt, E, twoE);
    node_kernel<<<(n + 63) / 64, 64, 0, stream>>>(
        maps, ws_list, ws_cnt, ws_S, ws_vd, E, n);
    writer_kernel<<<n, BLK, 0, stream>>>(
        maps, ws_list, ws_cnt, ws_S, ws_vd, out, E, ld);
}

// Round 10
// 102.137 us; speedup vs baseline: 1.0503x; 1.0503x over previous
//
#include <hip/hip_runtime.h>
#include <math.h>

// LaplacianBuilder: N=2048 nodes, DEG=16, D=4, E=32768 (2E=65536 directed)
// out = dense (8192 x 8192) fp32, 256 MB.
// v10: HYBRID. hipMemsetAsync zeros the 256MB output at the proven ~7 TB/s
// fill rate (our LDS-lookup writer only reached ~4 TB/s), then sparse
// scatter of the ~1.6% nonzero blocks:
//   memset(out) -> memset(cnt) -> build_lists -> node (diag block direct to
//   out) -> scatter pass1 (r,c)=W -> scatter pass2 (c,r)=W^T (wins, ref order)
// No fp atomics, no nt-stores (R9: nt = +12us), no vedge round-trip.

#define NNODES 2048
#define MAXDEG 96   // per-node directed-degree capacity (mean 32, huge margin)
#define BLK 256

// ---------------------------------------------------------------------------
// K1: per directed edge e in [0,2E): append (nbr<<20 | t<<19 | u) to
// list[ei[0][e]] (lists drive only the per-node Gram gather now).
// ---------------------------------------------------------------------------
__global__ void build_lists_kernel(const int* __restrict__ ei,
                                   int* __restrict__ lists,
                                   int* __restrict__ cnts,
                                   int E, int twoE) {
    int e = blockIdx.x * blockDim.x + threadIdx.x;
    if (e >= twoE) return;
    int node = ei[e];
    int nbr = ei[twoE + e];
    int t = (e >= E) ? 1 : 0;
    int u = t ? (e - E) : e;
    int slot = atomicAdd(&cnts[node], 1);
    if (slot < MAXDEG)
        lists[(size_t)node * MAXDEG + slot] = (nbr << 20) | (t << 19) | u;
}

// ---------------------------------------------------------------------------
// Jacobi rotation on (P,Q), compile-time indices -> stays in registers
// ---------------------------------------------------------------------------
template <int P, int Q>
__device__ __forceinline__ void jrot(float a[4][4], float v[4][4]) {
    float apq = a[P][Q];
    if (fabsf(apq) < 1e-12f) return;
    float theta = (a[Q][Q] - a[P][P]) / (2.0f * apq);
    float t = 1.0f / (fabsf(theta) + sqrtf(theta * theta + 1.0f));
    t = (theta < 0.0f) ? -t : t;
    float c = 1.0f / sqrtf(t * t + 1.0f);
    float s = t * c;
    #pragma unroll
    for (int k = 0; k < 4; ++k) {
        float akp = a[k][P], akq = a[k][Q];
        a[k][P] = c * akp - s * akq;
        a[k][Q] = s * akp + c * akq;
    }
    #pragma unroll
    for (int k = 0; k < 4; ++k) {
        float apk = a[P][k], aqk = a[Q][k];
        a[P][k] = c * apk - s * aqk;
        a[Q][k] = s * apk + c * aqk;
    }
    #pragma unroll
    for (int k = 0; k < 4; ++k) {
        float vkp = v[k][P], vkq = v[k][Q];
        v[k][P] = c * vkp - s * vkq;
        v[k][Q] = s * vkp + c * vkq;
    }
}

// ---------------------------------------------------------------------------
// K2: per node: gather-sum Gram over listed directed edges, eigh(G+I) via
// 6 Jacobi sweeps, S=(G+I)^(-1/2) -> ws; diag block clip(S G S) -> out.
// ---------------------------------------------------------------------------
__global__ void __launch_bounds__(64)
node_kernel(const float* __restrict__ maps,
            const int* __restrict__ lists,
            const int* __restrict__ cnts,
            float* __restrict__ Smat,
            float* __restrict__ out,
            int E, int n, int ld) {
    int node = blockIdx.x * blockDim.x + threadIdx.x;
    if (node >= n) return;
    float gm[4][4];
    #pragma unroll
    for (int i = 0; i < 4; ++i)
        #pragma unroll
        for (int j = 0; j < 4; ++j) gm[i][j] = 0.0f;
    int cnt = cnts[node];
    if (cnt > MAXDEG) cnt = MAXDEG;
    const int* myl = lists + (size_t)node * MAXDEG;
    #pragma unroll 4
    for (int j = 0; j < cnt; ++j) {
        int entry = myl[j];
        int t = (entry >> 19) & 1;
        int u = entry & 0x7FFF;
        int e = t ? (E + u) : u;
        const float4* mp = reinterpret_cast<const float4*>(maps + (size_t)e * 16);
        float4 q0 = mp[0], q1 = mp[1], q2 = mp[2], q3 = mp[3];
        float m[4][4] = {{q0.x, q0.y, q0.z, q0.w}, {q1.x, q1.y, q1.z, q1.w},
                         {q2.x, q2.y, q2.z, q2.w}, {q3.x, q3.y, q3.z, q3.w}};
        #pragma unroll
        for (int i = 0; i < 4; ++i)
            #pragma unroll
            for (int jj = 0; jj < 4; ++jj)
                gm[i][jj] += m[0][i] * m[0][jj] + m[1][i] * m[1][jj] +
                             m[2][i] * m[2][jj] + m[3][i] * m[3][jj];
    }
    float a[4][4], v[4][4];
    #pragma unroll
    for (int i = 0; i < 4; ++i)
        #pragma unroll
        for (int j = 0; j < 4; ++j) {
            a[i][j] = gm[i][j] + (i == j ? 1.0f : 0.0f);
            v[i][j] = (i == j) ? 1.0f : 0.0f;
        }
    #pragma unroll
    for (int sweep = 0; sweep < 6; ++sweep) {
        jrot<0, 1>(a, v); jrot<0, 2>(a, v); jrot<0, 3>(a, v);
        jrot<1, 2>(a, v); jrot<1, 3>(a, v); jrot<2, 3>(a, v);
    }
    float ir[4];
    #pragma unroll
    for (int m = 0; m < 4; ++m)
        ir[m] = 1.0f / sqrtf(fmaxf(a[m][m], 1e-8f));
    float s[4][4];
    #pragma unroll
    for (int i = 0; i < 4; ++i)
        #pragma unroll
        for (int j = 0; j < 4; ++j)
            s[i][j] = v[i][0] * v[j][0] * ir[0] + v[i][1] * v[j][1] * ir[1] +
                      v[i][2] * v[j][2] * ir[2] + v[i][3] * v[j][3] * ir[3];
    float4* sp = reinterpret_cast<float4*>(Smat + (size_t)node * 16);
    sp[0] = make_float4(s[0][0], s[0][1], s[0][2], s[0][3]);
    sp[1] = make_float4(s[1][0], s[1][1], s[1][2], s[1][3]);
    sp[2] = make_float4(s[2][0], s[2][1], s[2][2], s[2][3]);
    sp[3] = make_float4(s[3][0], s[3][1], s[3][2], s[3][3]);
    float t1[4][4];
    #pragma unroll
    for (int i = 0; i < 4; ++i)
        #pragma unroll
        for (int j = 0; j < 4; ++j)
            t1[i][j] = s[i][0] * gm[0][j] + s[i][1] * gm[1][j] +
                       s[i][2] * gm[2][j] + s[i][3] * gm[3][j];
    // diag block clip(S G S) directly into out
    size_t base = ((size_t)node * 4) * (size_t)ld + (size_t)node * 4;
    #pragma unroll
    for (int i = 0; i < 4; ++i) {
        float r0 = t1[i][0] * s[0][0] + t1[i][1] * s[1][0] + t1[i][2] * s[2][0] + t1[i][3] * s[3][0];
        float r1 = t1[i][0] * s[0][1] + t1[i][1] * s[1][1] + t1[i][2] * s[2][1] + t1[i][3] * s[3][1];
        float r2 = t1[i][0] * s[0][2] + t1[i][1] * s[1][2] + t1[i][2] * s[2][2] + t1[i][3] * s[3][2];
        float r3 = t1[i][0] * s[0][3] + t1[i][1] * s[1][3] + t1[i][2] * s[2][3] + t1[i][3] * s[3][3];
        *reinterpret_cast<float4*>(out + base + (size_t)i * ld) =
            make_float4(fminf(fmaxf(r0, -1.0f), 1.0f),
                        fminf(fmaxf(r1, -1.0f), 1.0f),
                        fminf(fmaxf(r2, -1.0f), 1.0f),
                        fminf(fmaxf(r3, -1.0f), 1.0f));
    }
}

// ---------------------------------------------------------------------------
// K3/K4: per undirected edge u: W = -clip(S_r (A^T B) S_c, -1, 1).
//   PASS 0: out[r,c] = W        (reference scatter #1)
//   PASS 1: out[c,r] = W^T      (reference scatter #2 — strictly after, wins)
// ---------------------------------------------------------------------------
template <int PASS>
__global__ void scatter_kernel(const float* __restrict__ maps,
                               const int* __restrict__ ei,
                               const float* __restrict__ Smat,
                               float* __restrict__ out,
                               int E, int twoE, int ld) {
    int u = blockIdx.x * blockDim.x + threadIdx.x;
    if (u >= E) return;
    int r = ei[u];
    int c = ei[twoE + u];
    const float4* ap = reinterpret_cast<const float4*>(maps + (size_t)u * 16);
    const float4* bp = reinterpret_cast<const float4*>(maps + (size_t)(E + u) * 16);
    float4 a0 = ap[0], a1 = ap[1], a2 = ap[2], a3 = ap[3];
    float4 b0 = bp[0], b1 = bp[1], b2 = bp[2], b3 = bp[3];
    float A[4][4] = {{a0.x, a0.y, a0.z, a0.w}, {a1.x, a1.y, a1.z, a1.w},
                     {a2.x, a2.y, a2.z, a2.w}, {a3.x, a3.y, a3.z, a3.w}};
    float B[4][4] = {{b0.x, b0.y, b0.z, b0.w}, {b1.x, b1.y, b1.z, b1.w},
                     {b2.x, b2.y, b2.z, b2.w}, {b3.x, b3.y, b3.z, b3.w}};
    float C[4][4];
    #pragma unroll
    for (int i = 0; i < 4; ++i)
        #pragma unroll
        for (int j = 0; j < 4; ++j)
            C[i][j] = A[0][i] * B[0][j] + A[1][i] * B[1][j] +
                      A[2][i] * B[2][j] + A[3][i] * B[3][j];
    const float4* srp = reinterpret_cast<const float4*>(Smat + (size_t)r * 16);
    const float4* scp = reinterpret_cast<const float4*>(Smat + (size_t)c * 16);
    float4 s0 = srp[0], s1 = srp[1], s2 = srp[2], s3 = srp[3];
    float Sr[4][4] = {{s0.x, s0.y, s0.z, s0.w}, {s1.x, s1.y, s1.z, s1.w},
                      {s2.x, s2.y, s2.z, s2.w}, {s3.x, s3.y, s3.z, s3.w}};
    float4 c0 = scp[0], c1 = scp[1], c2 = scp[2], c3 = scp[3];
    float Sc[4][4] = {{c0.x, c0.y, c0.z, c0.w}, {c1.x, c1.y, c1.z, c1.w},
                      {c2.x, c2.y, c2.z, c2.w}, {c3.x, c3.y, c3.z, c3.w}};
    float t1m[4][4];
    #pragma unroll
    for (int i = 0; i < 4; ++i)
        #pragma unroll
        for (int j = 0; j < 4; ++j)
            t1m[i][j] = Sr[i][0] * C[0][j] + Sr[i][1] * C[1][j] +
                        Sr[i][2] * C[2][j] + Sr[i][3] * C[3][j];
    float W[4][4];   // W = -clip(T)
    #pragma unroll
    for (int i = 0; i < 4; ++i)
        #pragma unroll
        for (int j = 0; j < 4; ++j) {
            float x = t1m[i][0] * Sc[0][j] + t1m[i][1] * Sc[1][j] +
                      t1m[i][2] * Sc[2][j] + t1m[i][3] * Sc[3][j];
            W[i][j] = -fminf(fmaxf(x, -1.0f), 1.0f);
        }
    if (PASS == 0) {
        size_t base = ((size_t)r * 4) * (size_t)ld + (size_t)c * 4;
        #pragma unroll
        for (int i = 0; i < 4; ++i)
            *reinterpret_cast<float4*>(out + base + (size_t)i * ld) =
                make_float4(W[i][0], W[i][1], W[i][2], W[i][3]);
    } else {
        size_t base = ((size_t)c * 4) * (size_t)ld + (size_t)r * 4;
        #pragma unroll
        for (int i = 0; i < 4; ++i)   // row i of W^T = column i of W
            *reinterpret_cast<float4*>(out + base + (size_t)i * ld) =
                make_float4(W[0][i], W[1][i], W[2][i], W[3][i]);
    }
}

extern "C" void kernel_launch(void* const* d_in, const int* in_sizes, int n_in,
                              void* d_out, int out_size, void* d_ws, size_t ws_size,
                              hipStream_t stream) {
    const float* maps = (const float*)d_in[0];
    const int* ei = (const int*)d_in[1];   // (2, 2E) int32
    int twoE = in_sizes[0] / 16;           // 65536
    int E = twoE / 2;                      // 32768
    int n = NNODES;
    int ld = n * 4;                        // 8192
    float* out = (float*)d_out;

    int*   ws_cnt  = (int*)d_ws;                              // n ints
    int*   ws_list = ws_cnt + n;                              // n*MAXDEG ints
    float* ws_S    = (float*)(ws_list + (size_t)n * MAXDEG);  // n*16 floats

    // zero the whole output at the hardware fill rate (~7 TB/s measured)
    (void)hipMemsetAsync(out, 0, (size_t)out_size * sizeof(float), stream);
    (void)hipMemsetAsync(ws_cnt, 0, (size_t)n * sizeof(int), stream);

    build_lists_kernel<<<(twoE + BLK - 1) / BLK, BLK, 0, stream>>>(
        ei, ws_list, ws_cnt, E, twoE);
    node_kernel<<<(n + 63) / 64, 64, 0, stream>>>(
        maps, ws_list, ws_cnt, ws_S, out, E, n, ld);
    scatter_kernel<0><<<(E + BLK - 1) / BLK, BLK, 0, stream>>>(
        maps, ei, ws_S, out, E, twoE, ld);
    scatter_kernel<1><<<(E + BLK - 1) / BLK, BLK, 0, stream>>>(
        maps, ei, ws_S, out, E, twoE, ld);
}

// Round 11
// 101.121 us; speedup vs baseline: 1.0609x; 1.0100x over previous
//
#include <hip/hip_runtime.h>
#include <math.h>

// LaplacianBuilder: N=2048 nodes, DEG=16, D=4, E=32768 (2E=65536 directed)
// out = dense (8192 x 8192) fp32, 256 MB.
// v11: R4 pipeline but writer SPLIT for occupancy:
//   memset(cnt) -> build_lists -> node (S, vdiag) -> edge (wdat[e] per
//   directed edge, transpose pre-applied) -> writer_lite (low-VGPR stream,
//   8 blocks/CU, cb-outer 4-store iterations, short colmap).
// Ledger: nt stores +12us (R9), memset+scatter +7us (R10), fused coop +145us
// (R6) -> all reverted.

#define NNODES 2048
#define MAXDEG 96   // per-node directed-degree capacity (mean 32, huge margin)
#define BLK 256

typedef float vfloat4 __attribute__((ext_vector_type(4)));

// ---------------------------------------------------------------------------
// K1: per directed edge e in [0,2E): append (nbr<<20 | t<<19 | u) to
// list[ei[0][e]].  t=1 for the reverse half (e>=E), u = undirected index.
// ---------------------------------------------------------------------------
__global__ void build_lists_kernel(const int* __restrict__ ei,
                                   int* __restrict__ lists,
                                   int* __restrict__ cnts,
                                   int E, int twoE) {
    int e = blockIdx.x * blockDim.x + threadIdx.x;
    if (e >= twoE) return;
    int node = ei[e];
    int nbr = ei[twoE + e];
    int t = (e >= E) ? 1 : 0;
    int u = t ? (e - E) : e;
    int slot = atomicAdd(&cnts[node], 1);
    if (slot < MAXDEG)
        lists[(size_t)node * MAXDEG + slot] = (nbr << 20) | (t << 19) | u;
}

// ---------------------------------------------------------------------------
// Jacobi rotation on (P,Q), compile-time indices -> stays in registers
// ---------------------------------------------------------------------------
template <int P, int Q>
__device__ __forceinline__ void jrot(float a[4][4], float v[4][4]) {
    float apq = a[P][Q];
    if (fabsf(apq) < 1e-12f) return;
    float theta = (a[Q][Q] - a[P][P]) / (2.0f * apq);
    float t = 1.0f / (fabsf(theta) + sqrtf(theta * theta + 1.0f));
    t = (theta < 0.0f) ? -t : t;
    float c = 1.0f / sqrtf(t * t + 1.0f);
    float s = t * c;
    #pragma unroll
    for (int k = 0; k < 4; ++k) {
        float akp = a[k][P], akq = a[k][Q];
        a[k][P] = c * akp - s * akq;
        a[k][Q] = s * akp + c * akq;
    }
    #pragma unroll
    for (int k = 0; k < 4; ++k) {
        float apk = a[P][k], aqk = a[Q][k];
        a[P][k] = c * apk - s * aqk;
        a[Q][k] = s * apk + c * aqk;
    }
    #pragma unroll
    for (int k = 0; k < 4; ++k) {
        float vkp = v[k][P], vkq = v[k][Q];
        v[k][P] = c * vkp - s * vkq;
        v[k][Q] = s * vkp + c * vkq;
    }
}

// ---------------------------------------------------------------------------
// K2: per node: gather-sum Gram over listed directed edges, eigh(G+I) via
// 6 Jacobi sweeps, S=(G+I)^(-1/2) -> Smat; vdiag = clip(S G S, -1, 1).
// ---------------------------------------------------------------------------
__global__ void __launch_bounds__(64)
node_kernel(const float* __restrict__ maps,
            const int* __restrict__ lists,
            const int* __restrict__ cnts,
            float* __restrict__ Smat,
            float* __restrict__ vdiag,
            int E, int n) {
    int node = blockIdx.x * blockDim.x + threadIdx.x;
    if (node >= n) return;
    float gm[4][4];
    #pragma unroll
    for (int i = 0; i < 4; ++i)
        #pragma unroll
        for (int j = 0; j < 4; ++j) gm[i][j] = 0.0f;
    int cnt = cnts[node];
    if (cnt > MAXDEG) cnt = MAXDEG;
    const int* myl = lists + (size_t)node * MAXDEG;
    #pragma unroll 4
    for (int j = 0; j < cnt; ++j) {
        int entry = myl[j];
        int t = (entry >> 19) & 1;
        int u = entry & 0x7FFF;
        int e = t ? (E + u) : u;
        const float4* mp = reinterpret_cast<const float4*>(maps + (size_t)e * 16);
        float4 q0 = mp[0], q1 = mp[1], q2 = mp[2], q3 = mp[3];
        float m[4][4] = {{q0.x, q0.y, q0.z, q0.w}, {q1.x, q1.y, q1.z, q1.w},
                         {q2.x, q2.y, q2.z, q2.w}, {q3.x, q3.y, q3.z, q3.w}};
        #pragma unroll
        for (int i = 0; i < 4; ++i)
            #pragma unroll
            for (int jj = 0; jj < 4; ++jj)
                gm[i][jj] += m[0][i] * m[0][jj] + m[1][i] * m[1][jj] +
                             m[2][i] * m[2][jj] + m[3][i] * m[3][jj];
    }
    float a[4][4], v[4][4];
    #pragma unroll
    for (int i = 0; i < 4; ++i)
        #pragma unroll
        for (int j = 0; j < 4; ++j) {
            a[i][j] = gm[i][j] + (i == j ? 1.0f : 0.0f);
            v[i][j] = (i == j) ? 1.0f : 0.0f;
        }
    #pragma unroll
    for (int sweep = 0; sweep < 6; ++sweep) {
        jrot<0, 1>(a, v); jrot<0, 2>(a, v); jrot<0, 3>(a, v);
        jrot<1, 2>(a, v); jrot<1, 3>(a, v); jrot<2, 3>(a, v);
    }
    float ir[4];
    #pragma unroll
    for (int m = 0; m < 4; ++m)
        ir[m] = 1.0f / sqrtf(fmaxf(a[m][m], 1e-8f));
    float s[4][4];
    #pragma unroll
    for (int i = 0; i < 4; ++i)
        #pragma unroll
        for (int j = 0; j < 4; ++j)
            s[i][j] = v[i][0] * v[j][0] * ir[0] + v[i][1] * v[j][1] * ir[1] +
                      v[i][2] * v[j][2] * ir[2] + v[i][3] * v[j][3] * ir[3];
    float4* sp = reinterpret_cast<float4*>(Smat + (size_t)node * 16);
    sp[0] = make_float4(s[0][0], s[0][1], s[0][2], s[0][3]);
    sp[1] = make_float4(s[1][0], s[1][1], s[1][2], s[1][3]);
    sp[2] = make_float4(s[2][0], s[2][1], s[2][2], s[2][3]);
    sp[3] = make_float4(s[3][0], s[3][1], s[3][2], s[3][3]);
    float t1[4][4];
    #pragma unroll
    for (int i = 0; i < 4; ++i)
        #pragma unroll
        for (int j = 0; j < 4; ++j)
            t1[i][j] = s[i][0] * gm[0][j] + s[i][1] * gm[1][j] +
                       s[i][2] * gm[2][j] + s[i][3] * gm[3][j];
    float4* vp = reinterpret_cast<float4*>(vdiag + (size_t)node * 16);
    #pragma unroll
    for (int i = 0; i < 4; ++i) {
        float r0 = t1[i][0] * s[0][0] + t1[i][1] * s[1][0] + t1[i][2] * s[2][0] + t1[i][3] * s[3][0];
        float r1 = t1[i][0] * s[0][1] + t1[i][1] * s[1][1] + t1[i][2] * s[2][1] + t1[i][3] * s[3][1];
        float r2 = t1[i][0] * s[0][2] + t1[i][1] * s[1][2] + t1[i][2] * s[2][2] + t1[i][3] * s[3][2];
        float r3 = t1[i][0] * s[0][3] + t1[i][1] * s[1][3] + t1[i][2] * s[2][3] + t1[i][3] * s[3][3];
        vp[i] = make_float4(fminf(fmaxf(r0, -1.0f), 1.0f),
                            fminf(fmaxf(r1, -1.0f), 1.0f),
                            fminf(fmaxf(r2, -1.0f), 1.0f),
                            fminf(fmaxf(r3, -1.0f), 1.0f));
    }
}

// ---------------------------------------------------------------------------
// K3: per DIRECTED edge e: compute the output block this edge contributes,
// transpose pre-applied for the reverse half, store to wdat[e] (64B).
//   e = u      (t=0): block (row[u],col[u]) = W = -clip(S_row (A^T B) S_col)
//   e = E + u  (t=1): block (col[u],row[u]) = W^T
// ---------------------------------------------------------------------------
__global__ void __launch_bounds__(BLK)
edge_kernel(const float* __restrict__ maps,
            const int* __restrict__ ei,
            const float* __restrict__ Smat,
            float* __restrict__ wdat,
            int E, int twoE) {
    int e = blockIdx.x * blockDim.x + threadIdx.x;
    if (e >= twoE) return;
    int t = (e >= E) ? 1 : 0;
    int u = t ? (e - E) : e;
    int rn = ei[u];            // row[u]
    int cn = ei[twoE + u];     // col[u]
    const float4* ap = reinterpret_cast<const float4*>(maps + (size_t)u * 16);
    const float4* bp = reinterpret_cast<const float4*>(maps + (size_t)(E + u) * 16);
    float4 a0 = ap[0], a1 = ap[1], a2 = ap[2], a3 = ap[3];
    float4 b0 = bp[0], b1 = bp[1], b2 = bp[2], b3 = bp[3];
    float A[4][4] = {{a0.x, a0.y, a0.z, a0.w}, {a1.x, a1.y, a1.z, a1.w},
                     {a2.x, a2.y, a2.z, a2.w}, {a3.x, a3.y, a3.z, a3.w}};
    float B[4][4] = {{b0.x, b0.y, b0.z, b0.w}, {b1.x, b1.y, b1.z, b1.w},
                     {b2.x, b2.y, b2.z, b2.w}, {b3.x, b3.y, b3.z, b3.w}};
    float C[4][4];
    #pragma unroll
    for (int i = 0; i < 4; ++i)
        #pragma unroll
        for (int j = 0; j < 4; ++j)
            C[i][j] = A[0][i] * B[0][j] + A[1][i] * B[1][j] +
                      A[2][i] * B[2][j] + A[3][i] * B[3][j];
    const float4* srp = reinterpret_cast<const float4*>(Smat + (size_t)rn * 16);
    const float4* scp = reinterpret_cast<const float4*>(Smat + (size_t)cn * 16);
    float4 s0 = srp[0], s1 = srp[1], s2 = srp[2], s3 = srp[3];
    float Sr[4][4] = {{s0.x, s0.y, s0.z, s0.w}, {s1.x, s1.y, s1.z, s1.w},
                      {s2.x, s2.y, s2.z, s2.w}, {s3.x, s3.y, s3.z, s3.w}};
    float4 c0 = scp[0], c1 = scp[1], c2 = scp[2], c3 = scp[3];
    float Sc[4][4] = {{c0.x, c0.y, c0.z, c0.w}, {c1.x, c1.y, c1.z, c1.w},
                      {c2.x, c2.y, c2.z, c2.w}, {c3.x, c3.y, c3.z, c3.w}};
    float t1m[4][4];
    #pragma unroll
    for (int i = 0; i < 4; ++i)
        #pragma unroll
        for (int j = 0; j < 4; ++j)
            t1m[i][j] = Sr[i][0] * C[0][j] + Sr[i][1] * C[1][j] +
                        Sr[i][2] * C[2][j] + Sr[i][3] * C[3][j];
    float W[4][4];
    #pragma unroll
    for (int i = 0; i < 4; ++i)
        #pragma unroll
        for (int j = 0; j < 4; ++j) {
            float x = t1m[i][0] * Sc[0][j] + t1m[i][1] * Sc[1][j] +
                      t1m[i][2] * Sc[2][j] + t1m[i][3] * Sc[3][j];
            W[i][j] = -fminf(fmaxf(x, -1.0f), 1.0f);
        }
    float4* wp = reinterpret_cast<float4*>(wdat + (size_t)e * 16);
    if (t) {   // store W^T
        wp[0] = make_float4(W[0][0], W[1][0], W[2][0], W[3][0]);
        wp[1] = make_float4(W[0][1], W[1][1], W[2][1], W[3][1]);
        wp[2] = make_float4(W[0][2], W[1][2], W[2][2], W[3][2]);
        wp[3] = make_float4(W[0][3], W[1][3], W[2][3], W[3][3]);
    } else {
        wp[0] = make_float4(W[0][0], W[0][1], W[0][2], W[0][3]);
        wp[1] = make_float4(W[1][0], W[1][1], W[1][2], W[1][3]);
        wp[2] = make_float4(W[2][0], W[2][1], W[2][2], W[2][3]);
        wp[3] = make_float4(W[3][0], W[3][1], W[3][2], W[3][3]);
    }
}

// ---------------------------------------------------------------------------
// K4: writer_lite. One workgroup per block-row r. LOW register pressure:
// copy <=cnt precomputed 64B blocks from wdat into LDS, build short colmap
// (t=0 pass then t=1 wins = reference overwrite order), then cb-outer
// stream: 1 LDS colmap read -> 4 independent 16B stores. 8 blocks/CU.
// ---------------------------------------------------------------------------
__global__ void __launch_bounds__(BLK, 8)
writer_kernel(const int* __restrict__ lists,
              const int* __restrict__ cnts,
              const float* __restrict__ wdat,
              const float* __restrict__ vdiag,
              float* __restrict__ out, int E, int ld) {
    int r = blockIdx.x;
    int tid = threadIdx.x;
    __shared__ short colmap[NNODES];             // 4 KB
    __shared__ vfloat4 s_dat[MAXDEG + 1][4];     // ~6.2 KB
    for (int i = tid; i < NNODES; i += BLK) colmap[i] = -1;

    int cnt = cnts[r];
    if (cnt > MAXDEG) cnt = MAXDEG;
    int col = -1, t = 0;
    if (tid < cnt) {
        int entry = lists[(size_t)r * MAXDEG + tid];
        col = entry >> 20;
        t = (entry >> 19) & 1;
        int u = entry & 0x7FFF;
        int e = t ? (E + u) : u;
        const vfloat4* wp = reinterpret_cast<const vfloat4*>(wdat + (size_t)e * 16);
        s_dat[tid][0] = wp[0];
        s_dat[tid][1] = wp[1];
        s_dat[tid][2] = wp[2];
        s_dat[tid][3] = wp[3];
    }
    if (tid < 4) {
        float4 dv = reinterpret_cast<const float4*>(vdiag + (size_t)r * 16)[tid];
        s_dat[MAXDEG][tid] = (vfloat4){dv.x, dv.y, dv.z, dv.w};
    }
    __syncthreads();                           // colmap cleared + s_dat ready
    if (tid < cnt && !t) colmap[col] = (short)tid;
    __syncthreads();                           // t=0 placed
    if (tid < cnt && t) colmap[col] = (short)tid;  // t=1 wins (reference order)
    if (tid == 0) colmap[r] = MAXDEG;          // diag (no self-edges)
    __syncthreads();

    size_t base = (size_t)(r * 4) * (size_t)ld;
    vfloat4* orow0 = reinterpret_cast<vfloat4*>(out + base);
    vfloat4* orow1 = reinterpret_cast<vfloat4*>(out + base + (size_t)ld);
    vfloat4* orow2 = reinterpret_cast<vfloat4*>(out + base + (size_t)2 * ld);
    vfloat4* orow3 = reinterpret_cast<vfloat4*>(out + base + (size_t)3 * ld);
    const vfloat4 zero = (vfloat4){0.f, 0.f, 0.f, 0.f};
    for (int cb = tid; cb < NNODES; cb += BLK) {
        int sl = colmap[cb];
        vfloat4 v0 = zero, v1 = zero, v2 = zero, v3 = zero;
        if (sl >= 0) {
            v0 = s_dat[sl][0]; v1 = s_dat[sl][1];
            v2 = s_dat[sl][2]; v3 = s_dat[sl][3];
        }
        orow0[cb] = v0;
        orow1[cb] = v1;
        orow2[cb] = v2;
        orow3[cb] = v3;
    }
}

extern "C" void kernel_launch(void* const* d_in, const int* in_sizes, int n_in,
                              void* d_out, int out_size, void* d_ws, size_t ws_size,
                              hipStream_t stream) {
    const float* maps = (const float*)d_in[0];
    const int* ei = (const int*)d_in[1];   // (2, 2E) int32
    int twoE = in_sizes[0] / 16;           // 65536
    int E = twoE / 2;                      // 32768
    int n = NNODES;
    int ld = n * 4;                        // 8192
    float* out = (float*)d_out;

    int*   ws_cnt  = (int*)d_ws;                              // n ints
    int*   ws_list = ws_cnt + n;                              // n*MAXDEG ints
    float* ws_S    = (float*)(ws_list + (size_t)n * MAXDEG);  // n*16 floats
    float* ws_vd   = ws_S + (size_t)n * 16;                   // n*16 floats
    float* ws_wdat = ws_vd + (size_t)n * 16;                  // 2E*16 floats (4 MB)

    (void)hipMemsetAsync(ws_cnt, 0, (size_t)n * sizeof(int), stream);
    build_lists_kernel<<<(twoE + BLK - 1) / BLK, BLK, 0, stream>>>(
        ei, ws_list, ws_cnt, E, twoE);
    node_kernel<<<(n + 63) / 64, 64, 0, stream>>>(
        maps, ws_list, ws_cnt, ws_S, ws_vd, E, n);
    edge_kernel<<<(twoE + BLK - 1) / BLK, BLK, 0, stream>>>(
        maps, ei, ws_S, ws_wdat, E, twoE);
    writer_kernel<<<n, BLK, 0, stream>>>(
        ws_list, ws_cnt, ws_wdat, ws_vd, out, E, ld);
}